// Round 3
// baseline (79.421 us; speedup 1.0000x reference)
//
#include <hip/hip_runtime.h>
#include <cstdint>

// B=4096, C=256, T=64, NH=4, ch=64. Eval gumbel path: argmax one-hot over
// softmax(qk*scale^2); a = v[:, argmax] (copy), ws[b] = sum_h pmax*ties.
//
// Persistent pipeline: grid=1024 blocks (exactly 4/CU resident, one
// generation), each block runs NB=4 batches. Per-wave counted-vmcnt queue
// never drains: next batch's q + k-round0 issue before round3's wait; the
// v-gather (inline asm global_load_dword) is consumed one batch later.
// Steady-state queue entering each iter: [q, r0 x4, gather] = 6.

typedef __attribute__((address_space(3))) void lds_t;
typedef const __attribute__((address_space(1))) void glb_t;

#define VWAIT(n) asm volatile("s_waitcnt vmcnt(" #n ")" ::: "memory")

constexpr int NB = 4;

__global__ __launch_bounds__(256, 4) void qkv_gumbel_attn(
    const float* __restrict__ q,
    const float* __restrict__ k,
    const float* __restrict__ v,
    float* __restrict__ out_a,
    float* __restrict__ out_ws)
{
    constexpr float SCALE = 0.35355339059327373f;  // 64^-0.25
    const int tid = threadIdx.x;
    const int h   = tid >> 6;   // head == wave
    const int l   = tid & 63;
    const int r4  = l >> 4;
    const int b0  = blockIdx.x * NB;

    __shared__ float sk[4][2][1024];   // 32 KB k double-buffer per wave
    __shared__ float sq[4][2][64];     // raw q, double-buffered per wave
    __shared__ float sws[4][NB];

    const float4* __restrict__ k4 = reinterpret_cast<const float4*>(k);

#define STAGE_K(b_, r_, buf_)                                                  \
    do {                                                                       \
        _Pragma("unroll")                                                      \
        for (int i_ = 0; i_ < 4; ++i_)                                         \
            __builtin_amdgcn_global_load_lds(                                  \
                (glb_t*)(k4 + (size_t)(b_) * 4096 + h * 1024 + (r_) * 256 +    \
                         i_ * 64 + l),                                         \
                (lds_t*)&sk[h][buf_][i_ * 256], 16, 0, 0);                     \
    } while (0)

#define STAGE_Q(b_, par_)                                                      \
    __builtin_amdgcn_global_load_lds(                                          \
        (glb_t*)(q + (size_t)(b_) * 256 + h * 64 + l),                         \
        (lds_t*)&sq[h][par_][0], 4, 0, 0)

    // Prologue: queue = [q, r0 x4, q-dup] (6). The duplicate q (same data,
    // same LDS slot, issued LAST) makes iter-0's queue shape match the
    // steady-state [q, r0 x4, g] so the counted waits below are uniform.
    STAGE_Q(b0, 0);
    STAGE_K(b0, 0, 0);
    STAGE_Q(b0, 0);

    float gv = 0.f;   // deferred gather value (batch it-1)

    for (int it = 0; it < NB; ++it) {
        const int b   = b0 + it;
        const int par = it & 1;
        const float* __restrict__ qb = sq[h][par];

        float a0 = 0.f, a1 = 0.f, a2 = 0.f, a3 = 0.f;

#define ROUND(r_)                                                              \
        do {                                                                   \
            const float* __restrict__ bufp_ = sk[h][(r_) & 1];                 \
            _Pragma("unroll")                                                  \
            for (int i_ = 0; i_ < 4; ++i_) {                                   \
                const float4 kv_ = *reinterpret_cast<const float4*>(           \
                    &bufp_[i_ * 256 + 4 * l]);                                 \
                const float qc_ = qb[(r_) * 16 + 4 * i_ + r4] * SCALE;         \
                a0 = fmaf(qc_, kv_.x * SCALE, a0);                             \
                a1 = fmaf(qc_, kv_.y * SCALE, a1);                             \
                a2 = fmaf(qc_, kv_.z * SCALE, a2);                             \
                a3 = fmaf(qc_, kv_.w * SCALE, a3);                             \
            }                                                                  \
        } while (0)

        STAGE_K(b, 1, 1);
        VWAIT(5);          // q(it), r0 done; gather(it-1) may still fly
        ROUND(0);

        STAGE_K(b, 2, 0);
        VWAIT(4);          // gather(it-1), r1 done
        if (it > 0) out_a[(size_t)(b - 1) * 256 + tid] = gv;
        ROUND(1);

        STAGE_K(b, 3, 1);
        VWAIT(4);          // prev store, r2 done
        ROUND(2);

        const int bn = (b + 1 < 4096) ? (b + 1) : 4095;  // clamped dummy at very end
        STAGE_Q(bn, par ^ 1);
        STAGE_K(bn, 0, 0);
        VWAIT(5);          // r3 done; q', r0' stay in flight through the tail
        ROUND(3);

        // ---- softmax / argmax: bitwise-identical to the absmax-0.0 kernel ----
        a0 += __shfl_xor(a0, 16); a0 += __shfl_xor(a0, 32);
        a1 += __shfl_xor(a1, 16); a1 += __shfl_xor(a1, 32);
        a2 += __shfl_xor(a2, 16); a2 += __shfl_xor(a2, 32);
        a3 += __shfl_xor(a3, 16); a3 += __shfl_xor(a3, 32);

        float m = fmaxf(fmaxf(a0, a1), fmaxf(a2, a3));
#pragma unroll
        for (int off = 1; off <= 8; off <<= 1) m = fmaxf(m, __shfl_xor(m, off));

        const float e0 = expf(a0 - m), e1 = expf(a1 - m),
                    e2 = expf(a2 - m), e3 = expf(a3 - m);
        float d = e0 + e1 + e2 + e3;
#pragma unroll
        for (int off = 1; off <= 8; off <<= 1) d += __shfl_xor(d, off);

        const float pm = 1.0f / d;   // == max_i(e_i/d) bitwise (e@argmax = 1.0f)

        uint64_t m0 = __ballot(e0 / d == pm) & 0xFFFFull;
        uint64_t m1 = __ballot(e1 / d == pm) & 0xFFFFull;
        uint64_t m2 = __ballot(e2 / d == pm) & 0xFFFFull;
        uint64_t m3 = __ballot(e3 / d == pm) & 0xFFFFull;

        const int cnt = __popcll(m0) + __popcll(m1) + __popcll(m2) + __popcll(m3);
        if (l == 0) sws[h][it] = pm * (float)cnt;

        const float* __restrict__ vrow =
            v + (size_t)b * 16384 + (size_t)(h * 64 + l) * 64;

        if (cnt == 1) {
            // Single argmax (the always-in-practice path): async gather,
            // consumed next iteration at the VWAIT(4) after ROUND(0).
            const uint64_t mm = m0 | (m1 << 16) | (m2 << 32) | (m3 << 48);
            const int bit = __ffsll((unsigned long long)mm) - 1; // 16*j + s
            const float* gaddr = vrow + 4 * (bit & 15) + (bit >> 4);
            asm volatile("global_load_dword %0, %1, off"
                         : "=v"(gv) : "v"(gaddr) : "memory");
        } else {
            // Tie path (measure-zero on random data): drain and do it simply.
            // Draining only SHORTENS the queue, which keeps later counted
            // waits correct (they pop at least as far as intended).
            VWAIT(0);
            float av = 0.f;
            while (m0) { int s = __ffsll((unsigned long long)m0) - 1; m0 &= m0 - 1; av += vrow[4 * s + 0]; }
            while (m1) { int s = __ffsll((unsigned long long)m1) - 1; m1 &= m1 - 1; av += vrow[4 * s + 1]; }
            while (m2) { int s = __ffsll((unsigned long long)m2) - 1; m2 &= m2 - 1; av += vrow[4 * s + 2]; }
            while (m3) { int s = __ffsll((unsigned long long)m3) - 1; m3 &= m3 - 1; av += vrow[4 * s + 3]; }
            gv = av;
        }
#undef ROUND
    }

    VWAIT(0);
    out_a[(size_t)(b0 + NB - 1) * 256 + tid] = gv;

    __syncthreads();
    if (tid < NB) {
        out_ws[b0 + tid] =
            ((sws[0][tid] + sws[1][tid]) + sws[2][tid]) + sws[3][tid];
    }
#undef STAGE_K
#undef STAGE_Q
}

extern "C" void kernel_launch(void* const* d_in, const int* in_sizes, int n_in,
                              void* d_out, int out_size, void* d_ws, size_t ws_size,
                              hipStream_t stream) {
    const float* q = (const float*)d_in[0];
    const float* k = (const float*)d_in[1];
    const float* v = (const float*)d_in[2];
    float* out_a  = (float*)d_out;                  // 4096*256 floats
    float* out_ws = out_a + (size_t)4096 * 256;     // 4096 floats
    qkv_gumbel_attn<<<dim3(1024), dim3(256), 0, stream>>>(q, k, v, out_a, out_ws);
}

// Round 4
// 78.891 us; speedup vs baseline: 1.0067x; 1.0067x over previous
//
#include <hip/hip_runtime.h>
#include <cstdint>

// B=4096, C=256, T=64, NH=4, ch=64. Eval gumbel path: argmax one-hot over
// softmax(qk*scale^2); a[b,c] = sum of tied v-columns, ws[b] = sum_h pmax*ties.
//
// Phase-split: mixing 1M scattered 64B v-gathers into the sequential 256MB
// k-stream degrades DRAM efficiency for both (R1-R3 all ~78us regardless of
// schedule). K1 = pure sequential stream (k,q) -> masks in d_ws + out_ws.
// K2 = pure scatter (v-gather by mask) -> out_a. Each phase runs its own
// traffic class at its own best rate.

__global__ __launch_bounds__(256) void qkv_phase1_logits(
    const float* __restrict__ q,
    const float* __restrict__ k,
    float* __restrict__ out_ws,
    unsigned long long* __restrict__ masks)
{
    constexpr float SCALE = 0.35355339059327373f; // 64^-0.25
    const int b   = blockIdx.x;
    const int tid = threadIdx.x;
    const int h   = tid >> 6;   // head == wave
    const int l   = tid & 63;
    const int r4  = l >> 4;

    __shared__ float sq[256];
    __shared__ float sws[4];

    sq[tid] = q[(size_t)b * 256 + tid] * SCALE;
    __syncthreads();

    // k head tile 64x64 floats = 1024 float4; f4 idx i*64+l covers
    // c = 4i + (l>>4), s = 4*(l&15)+j. Pure sequential stream, VGPR pipelined.
    const float4* __restrict__ k4 = reinterpret_cast<const float4*>(k);
    const size_t kbase = (size_t)b * 4096 + (size_t)h * 1024;

    float a0 = 0.f, a1 = 0.f, a2 = 0.f, a3 = 0.f;
#pragma unroll
    for (int i = 0; i < 16; ++i) {
        const float  qc = sq[h * 64 + 4 * i + r4];
        const float4 kv = k4[kbase + (size_t)(i * 64 + l)];
        a0 = fmaf(qc, kv.x * SCALE, a0);
        a1 = fmaf(qc, kv.y * SCALE, a1);
        a2 = fmaf(qc, kv.z * SCALE, a2);
        a3 = fmaf(qc, kv.w * SCALE, a3);
    }
    a0 += __shfl_xor(a0, 16); a0 += __shfl_xor(a0, 32);
    a1 += __shfl_xor(a1, 16); a1 += __shfl_xor(a1, 32);
    a2 += __shfl_xor(a2, 16); a2 += __shfl_xor(a2, 32);
    a3 += __shfl_xor(a3, 16); a3 += __shfl_xor(a3, 32);

    float m = fmaxf(fmaxf(a0, a1), fmaxf(a2, a3));
#pragma unroll
    for (int off = 1; off <= 8; off <<= 1) m = fmaxf(m, __shfl_xor(m, off));

    const float e0 = expf(a0 - m), e1 = expf(a1 - m),
                e2 = expf(a2 - m), e3 = expf(a3 - m);
    float d = e0 + e1 + e2 + e3;
#pragma unroll
    for (int off = 1; off <= 8; off <<= 1) d += __shfl_xor(d, off);

    // p at argmax is expf(0)/d == 1.0f/d exactly; ties via float equality
    // on p, exactly as the reference. (absmax 0.0 in R2/R3 with this form.)
    const float pm = 1.0f / d;

    const uint64_t m0 = __ballot(e0 / d == pm) & 0xFFFFull;
    const uint64_t m1 = __ballot(e1 / d == pm) & 0xFFFFull;
    const uint64_t m2 = __ballot(e2 / d == pm) & 0xFFFFull;
    const uint64_t m3 = __ballot(e3 / d == pm) & 0xFFFFull;
    const uint64_t mm = m0 | (m1 << 16) | (m2 << 32) | (m3 << 48);
    const int cnt = __popcll((unsigned long long)mm);

    if (l == 0) {
        masks[(size_t)b * 4 + h] = mm;
        sws[h] = pm * (float)cnt;
    }
    __syncthreads();
    if (tid == 0) out_ws[b] = ((sws[0] + sws[1]) + sws[2]) + sws[3];
}

__global__ __launch_bounds__(256) void qkv_phase2_gather(
    const float* __restrict__ v,
    const unsigned long long* __restrict__ masks,
    float* __restrict__ out_a)
{
    const int b   = blockIdx.x;
    const int tid = threadIdx.x;
    const int h   = tid >> 6;
    const int l   = tid & 63;

    // Wave-uniform mask (compiler scalarizes the load).
    uint64_t mm = masks[(size_t)b * 4 + h];

    // Lane l -> output channel h*64+l; gather element(s) s = 4*(bit&15)+(bit>>4)
    // from its 256B v-row. Typically exactly one bit set.
    const float* __restrict__ vrow =
        v + (size_t)b * 16384 + (size_t)(h * 64 + l) * 64;

    float a = 0.f;
    while (mm) {
        const int bit = __ffsll((unsigned long long)mm) - 1;
        mm &= mm - 1;
        a += vrow[4 * (bit & 15) + (bit >> 4)];
    }
    out_a[(size_t)b * 256 + tid] = a;
}

extern "C" void kernel_launch(void* const* d_in, const int* in_sizes, int n_in,
                              void* d_out, int out_size, void* d_ws, size_t ws_size,
                              hipStream_t stream) {
    const float* q = (const float*)d_in[0];
    const float* k = (const float*)d_in[1];
    const float* v = (const float*)d_in[2];
    float* out_a  = (float*)d_out;                  // 4096*256 floats
    float* out_ws = out_a + (size_t)4096 * 256;     // 4096 floats
    unsigned long long* masks = (unsigned long long*)d_ws;  // 16384 * 8B = 128 KB

    qkv_phase1_logits<<<dim3(4096), dim3(256), 0, stream>>>(q, k, out_ws, masks);
    qkv_phase2_gather<<<dim3(4096), dim3(256), 0, stream>>>(v, masks, out_a);
}